// Round 14
// baseline (828.450 us; speedup 1.0000x reference)
//
#include <hip/hip_runtime.h>
#include <hip/hip_bf16.h>
#include <math.h>

typedef __attribute__((ext_vector_type(8))) short short8;
typedef __attribute__((ext_vector_type(4))) float floatx4;

__device__ __forceinline__ unsigned short bfb(float x) {
    union { __hip_bfloat16 h; unsigned short u; } c;
    c.h = __float2bfloat16(x);
    return c.u;
}
__device__ __forceinline__ float bf2f(unsigned short u) {
    union { unsigned int i; float f; } c;
    c.i = ((unsigned int)u) << 16;
    return c.f;
}
__device__ __forceinline__ float bflo(unsigned u) {
    union { unsigned int i; float f; } c;
    c.i = u << 16;
    return c.f;
}
__device__ __forceinline__ float bfhi(unsigned u) {
    union { unsigned int i; float f; } c;
    c.i = u & 0xffff0000u;
    return c.f;
}

// ---------------- bucketed CSR build v3 (R13) ----------------

__global__ __launch_bounds__(256) void k_bhist(const int* __restrict__ dst, int* __restrict__ bcnt, int E) {
    __shared__ int h[512];
    int t = threadIdx.x;
    for (int i = t; i < 512; i += 256) h[i] = 0;
    __syncthreads();
    int step = gridDim.x * 256;
    for (int i = blockIdx.x * 256 + t; i < E; i += step) atomicAdd(&h[dst[i] >> 8], 1);
    __syncthreads();
    for (int i = t; i < 512; i += 256) if (h[i]) atomicAdd(&bcnt[i], h[i]);
}

__global__ __launch_bounds__(512) void k_scanBkt(const int* __restrict__ bcnt, int* __restrict__ boff,
                                                 int* __restrict__ bcur, int nb, int E) {
    __shared__ int s[512];
    int t = threadIdx.x;
    int v = (t < nb) ? bcnt[t] : 0;
    s[t] = v;
    __syncthreads();
    for (int off = 1; off < 512; off <<= 1) {
        int x = (t >= off) ? s[t - off] : 0;
        __syncthreads();
        s[t] += x;
        __syncthreads();
    }
    if (t < nb) { boff[t] = s[t] - v; bcur[t] = s[t] - v; }
    if (t == 0) boff[nb] = E;
}

#define PCHUNK 8192

__global__ __launch_bounds__(256) void k_partA(const int* __restrict__ src, const int* __restrict__ dst,
                                               int* __restrict__ bcur, unsigned* __restrict__ ebuf, int E) {
    __shared__ int h[512];
    __shared__ int base[512];
    int t = threadIdx.x;
    for (int i = t; i < 512; i += 256) h[i] = 0;
    __syncthreads();
    int start = blockIdx.x * PCHUNK;
    int end = start + PCHUNK < E ? start + PCHUNK : E;
    for (int i = start + t; i < end; i += 256) atomicAdd(&h[dst[i] >> 8], 1);
    __syncthreads();
    for (int i = t; i < 512; i += 256) {
        int c = h[i];
        base[i] = c ? atomicAdd(&bcur[i], c) : 0;
        h[i] = 0;
    }
    __syncthreads();
    for (int i = start + t; i < end; i += 256) {
        int d = dst[i];
        int b = d >> 8;
        int r = atomicAdd(&h[b], 1);
        ebuf[base[b] + r] = ((unsigned)src[i] << 8) | (unsigned)(d & 255);
    }
}

__global__ __launch_bounds__(256) void k_finish(const unsigned* __restrict__ ebuf, const int* __restrict__ boff,
                                                int* __restrict__ row_off, float* __restrict__ dinv,
                                                int* __restrict__ csr, int N, int E) {
    __shared__ int h[256];
    __shared__ int sc[256];
    __shared__ int cur[256];
    int b = blockIdx.x, t = threadIdx.x;
    h[t] = 0;
    __syncthreads();
    int beg = boff[b], end = boff[b + 1];
    for (int e = beg + t; e < end; e += 256) atomicAdd(&h[ebuf[e] & 255], 1);
    __syncthreads();
    int v = h[t];
    sc[t] = v;
    __syncthreads();
    for (int off = 1; off < 256; off <<= 1) {
        int x = (t >= off) ? sc[t - off] : 0;
        __syncthreads();
        sc[t] += x;
        __syncthreads();
    }
    int node = (b << 8) + t;
    int excl = beg + sc[t] - v;
    if (node < N) {
        row_off[node] = excl;
        dinv[node] = rsqrtf((float)(v > 1 ? v : 1));
    }
    cur[t] = excl;
    if (b == 0 && t == 0) row_off[N] = E;
    __syncthreads();
    for (int e = beg + t; e < end; e += 256) {
        unsigned ed = ebuf[e];
        int pos = atomicAdd(&cur[ed & 255], 1);
        csr[pos] = (int)(ed >> 8);
    }
}

// ---------------- feat -> bf16 pre-scaled (node-major, 16-dim layer only) ----------------

__global__ __launch_bounds__(256) void k_feat16(const float* __restrict__ feat, const float* __restrict__ dinv,
                                                unsigned short* __restrict__ featd, int total) {
    int i = blockIdx.x * 256 + threadIdx.x;
    if (i < total) featd[i] = bfb(feat[i] * dinv[i >> 4]);
}

// ---------------- 16-dim Chebyshev aggregation (node-major bf16 gather; table 3.2MB) ----------------

__global__ __launch_bounds__(256) void k_aggr16(const unsigned short* __restrict__ Xd, const float* __restrict__ Z,
                                                const float* __restrict__ dinv,
                                                const int* __restrict__ row_off, const int* __restrict__ csr,
                                                float* __restrict__ out, unsigned short* __restrict__ outd,
                                                float alpha, float beta, int N) {
    const int D = 16;
    int t = blockIdx.x * blockDim.x + threadIdx.x;
    int node = t / D;
    int d = t % D;
    if (node >= N) return;
    int beg = row_off[node], end = row_off[node + 1];
    float a0 = 0.f, a1 = 0.f, a2 = 0.f, a3 = 0.f;
    int j = beg;
    for (; j + 3 < end; j += 4) {
        int s0 = csr[j], s1 = csr[j + 1], s2 = csr[j + 2], s3 = csr[j + 3];
        a0 += bf2f(Xd[s0 * D + d]);
        a1 += bf2f(Xd[s1 * D + d]);
        a2 += bf2f(Xd[s2 * D + d]);
        a3 += bf2f(Xd[s3 * D + d]);
    }
    for (; j < end; ++j) a0 += bf2f(Xd[csr[j] * D + d]);
    float acc = (a0 + a1) + (a2 + a3);
    float dn = dinv[node];
    float v = alpha * dn * acc;
    if (Z) v += beta * Z[node * D + d];
    out[node * D + d] = v;
    if (outd) outd[node * D + d] = bfb(v * dn);
}

// ---------------- 64-dim sliced gathers ----------------
// Tables slice-major: T[s][node][8 dims], 8 sub-tables of 1.6MB. slice = blockIdx&7 ->
// round-robin XCD dispatch pins one sub-table per XCD L2 (4MiB): random feature reads
// become L2 hits; only csr streams (sequential). R12/R13 showed gathers pinned at
// 99MB L3 fetch (~2.4 TB/s line rate) with node-major tables.

#define SLICE_NPB 128

__global__ __launch_bounds__(256) void k_aggr64s(const unsigned short* __restrict__ Tbl,
                                                 const float* __restrict__ Z, const float* __restrict__ dinv,
                                                 const int* __restrict__ row_off, const int* __restrict__ csr,
                                                 float* __restrict__ out, unsigned short* __restrict__ outd,
                                                 float alpha, float beta, int N) {
    int slice = blockIdx.x & 7;
    int chunk = blockIdx.x >> 3;
    int t = threadIdx.x;
    int wi = t >> 6;
    int lane = t & 63;
    int grp = lane >> 3;
    int gl = lane & 7;
    const unsigned short* T = Tbl + (size_t)slice * N * 8;
#pragma unroll 1
    for (int it = 0; it < SLICE_NPB / 32; ++it) {
        int node = chunk * SLICE_NPB + it * 32 + wi * 8 + grp;
        bool alive = node < N;
        int nn = alive ? node : N - 1;
        int beg = row_off[nn], end = alive ? row_off[nn + 1] : row_off[nn];
        float a0 = 0.f, a1 = 0.f, a2 = 0.f, a3 = 0.f, a4 = 0.f, a5 = 0.f, a6 = 0.f, a7 = 0.f;
        for (int j = beg + gl; j < end; j += 8) {
            int s = csr[j];
            uint4 w = *(const uint4*)&T[(size_t)s * 8];
            a0 += bflo(w.x); a1 += bfhi(w.x);
            a2 += bflo(w.y); a3 += bfhi(w.y);
            a4 += bflo(w.z); a5 += bfhi(w.z);
            a6 += bflo(w.w); a7 += bfhi(w.w);
        }
#pragma unroll
        for (int o = 1; o < 8; o <<= 1) {
            a0 += __shfl_xor(a0, o); a1 += __shfl_xor(a1, o);
            a2 += __shfl_xor(a2, o); a3 += __shfl_xor(a3, o);
            a4 += __shfl_xor(a4, o); a5 += __shfl_xor(a5, o);
            a6 += __shfl_xor(a6, o); a7 += __shfl_xor(a7, o);
        }
        if (gl == 0 && alive) {
            float dn = dinv[node];
            float ad = alpha * dn;
            float v[8] = { ad * a0, ad * a1, ad * a2, ad * a3, ad * a4, ad * a5, ad * a6, ad * a7 };
            if (Z) {
                const float* zp = &Z[(size_t)node * 64 + slice * 8];
                float4 z0 = *(const float4*)zp;
                float4 z1 = *(const float4*)(zp + 4);
                v[0] += beta * z0.x; v[1] += beta * z0.y; v[2] += beta * z0.z; v[3] += beta * z0.w;
                v[4] += beta * z1.x; v[5] += beta * z1.y; v[6] += beta * z1.z; v[7] += beta * z1.w;
            }
            float* op = &out[(size_t)node * 64 + slice * 8];
            float4 r0 = { v[0], v[1], v[2], v[3] };
            float4 r1 = { v[4], v[5], v[6], v[7] };
            *(float4*)op = r0;
            *(float4*)(op + 4) = r1;
            if (outd) {
                uint4 u;
                u.x = (unsigned)bfb(v[0] * dn) | ((unsigned)bfb(v[1] * dn) << 16);
                u.y = (unsigned)bfb(v[2] * dn) | ((unsigned)bfb(v[3] * dn) << 16);
                u.z = (unsigned)bfb(v[4] * dn) | ((unsigned)bfb(v[5] * dn) << 16);
                u.w = (unsigned)bfb(v[6] * dn) | ((unsigned)bfb(v[7] * dn) << 16);
                *(uint4*)&outd[((size_t)slice * N + node) * 8] = u;
            }
        }
    }
}

__global__ __launch_bounds__(256) void k_e2s(const unsigned short* __restrict__ Tbl, const float* __restrict__ pbuf,
                                             const int* __restrict__ row_off, const int* __restrict__ csr,
                                             const float* __restrict__ dinv, float* __restrict__ out,
                                             unsigned short* __restrict__ outd, int N) {
    int slice = blockIdx.x & 7;
    int chunk = blockIdx.x >> 3;
    int t = threadIdx.x;
    int wi = t >> 6;
    int lane = t & 63;
    int grp = lane >> 3;
    int gl = lane & 7;
    const unsigned short* T = Tbl + (size_t)slice * N * 8;
#pragma unroll 1
    for (int it = 0; it < SLICE_NPB / 32; ++it) {
        int node = chunk * SLICE_NPB + it * 32 + wi * 8 + grp;
        bool alive = node < N;
        int nn = alive ? node : N - 1;
        int beg = row_off[nn], end = alive ? row_off[nn + 1] : row_off[nn];
        float a0 = -INFINITY, a1 = -INFINITY, a2 = -INFINITY, a3 = -INFINITY;
        float a4 = -INFINITY, a5 = -INFINITY, a6 = -INFINITY, a7 = -INFINITY;
        for (int j = beg + gl; j < end; j += 8) {
            int s = csr[j];
            uint4 w = *(const uint4*)&T[(size_t)s * 8];
            a0 = fmaxf(a0, -bflo(w.x)); a1 = fmaxf(a1, -bfhi(w.x));
            a2 = fmaxf(a2, -bflo(w.y)); a3 = fmaxf(a3, -bfhi(w.y));
            a4 = fmaxf(a4, -bflo(w.z)); a5 = fmaxf(a5, -bfhi(w.z));
            a6 = fmaxf(a6, -bflo(w.w)); a7 = fmaxf(a7, -bfhi(w.w));
        }
#pragma unroll
        for (int o = 1; o < 8; o <<= 1) {
            a0 = fmaxf(a0, __shfl_xor(a0, o)); a1 = fmaxf(a1, __shfl_xor(a1, o));
            a2 = fmaxf(a2, __shfl_xor(a2, o)); a3 = fmaxf(a3, __shfl_xor(a3, o));
            a4 = fmaxf(a4, __shfl_xor(a4, o)); a5 = fmaxf(a5, __shfl_xor(a5, o));
            a6 = fmaxf(a6, __shfl_xor(a6, o)); a7 = fmaxf(a7, __shfl_xor(a7, o));
        }
        if (gl == 0 && alive) {
            float r[8] = { 0.f, 0.f, 0.f, 0.f, 0.f, 0.f, 0.f, 0.f };
            if (end > beg) {
                const float* pv = &pbuf[(size_t)node * 64 + slice * 8];
                float4 p0 = *(const float4*)pv;
                float4 p1 = *(const float4*)(pv + 4);
                r[0] = fmaxf(p0.x + a0, 0.f); r[1] = fmaxf(p0.y + a1, 0.f);
                r[2] = fmaxf(p0.z + a2, 0.f); r[3] = fmaxf(p0.w + a3, 0.f);
                r[4] = fmaxf(p1.x + a4, 0.f); r[5] = fmaxf(p1.y + a5, 0.f);
                r[6] = fmaxf(p1.z + a6, 0.f); r[7] = fmaxf(p1.w + a7, 0.f);
            }
            float* op = &out[(size_t)node * 64 + slice * 8];
            float4 r0 = { r[0], r[1], r[2], r[3] };
            float4 r1 = { r[4], r[5], r[6], r[7] };
            *(float4*)op = r0;
            *(float4*)(op + 4) = r1;
            float dn = dinv[node];
            uint4 u;
            u.x = (unsigned)bfb(r[0] * dn) | ((unsigned)bfb(r[1] * dn) << 16);
            u.y = (unsigned)bfb(r[2] * dn) | ((unsigned)bfb(r[3] * dn) << 16);
            u.z = (unsigned)bfb(r[4] * dn) | ((unsigned)bfb(r[5] * dn) << 16);
            u.w = (unsigned)bfb(r[6] * dn) | ((unsigned)bfb(r[7] * dn) << 16);
            *(uint4*)&outd[((size_t)slice * N + node) * 8] = u;
        }
    }
}

// ---------------- Cheb matmul via MFMA 16x16x32 bf16 (R11-verified) ----------------

template <int KDIM>
__global__ __launch_bounds__(256) void k_cheb_m(const float* __restrict__ X0, const float* __restrict__ X1,
                                                const float* __restrict__ X2, const float* __restrict__ W,
                                                const float* __restrict__ b, float* __restrict__ out, int N) {
    constexpr int KT = (KDIM == 16) ? 64 : 3 * KDIM;
    constexpr int SX = KT + 8;
    __shared__ unsigned short Xs[64 * SX];
    __shared__ unsigned short Ws[64 * SX];
    int t = threadIdx.x;

    {
        int sn = t & 63;
        int gn = blockIdx.x * 64 + sn; if (gn >= N) gn = N - 1;
        int k0 = (t >> 6) * (KDIM / 4);
        const float* Xp[3] = { X0, X1, X2 };
#pragma unroll
        for (int a = 0; a < 3; ++a) {
            const float* X = Xp[a];
#pragma unroll
            for (int i = 0; i < KDIM / 16; ++i) {
                float4 v = *(const float4*)&X[(size_t)gn * KDIM + k0 + 4 * i];
                ushort4 u = { bfb(v.x), bfb(v.y), bfb(v.z), bfb(v.w) };
                *(ushort4*)&Xs[sn * SX + a * KDIM + k0 + 4 * i] = u;
            }
        }
        if (KDIM == 16) {
            int kp = 48 + (t >> 6) * 4;
            ushort4 z = { 0, 0, 0, 0 };
            *(ushort4*)&Xs[sn * SX + kp] = z;
        }
    }
    for (int idx = t; idx < 3 * KDIM * 64; idx += 256) {
        int a = idx / (KDIM * 64);
        int r = idx % (KDIM * 64);
        int k = r >> 6, n = r & 63;
        Ws[n * SX + a * KDIM + k] = bfb(W[idx]);
    }
    if (KDIM == 16) {
        for (int idx = t; idx < 1024; idx += 256) {
            int n = idx & 63, k = 48 + (idx >> 6);
            Ws[n * SX + k] = 0;
        }
    }
    __syncthreads();

    int wave = t >> 6, lane = t & 63;
    int fi = lane & 15, quad = lane >> 4;
    int arow = wave * 16 + fi;

    floatx4 acc0 = {0.f,0.f,0.f,0.f}, acc1 = {0.f,0.f,0.f,0.f}, acc2 = {0.f,0.f,0.f,0.f}, acc3 = {0.f,0.f,0.f,0.f};
#pragma unroll
    for (int ks = 0; ks < KT / 32; ++ks) {
        short8 af = *(const short8*)&Xs[arow * SX + ks * 32 + quad * 8];
        short8 b0 = *(const short8*)&Ws[(0 * 16 + fi) * SX + ks * 32 + quad * 8];
        short8 b1 = *(const short8*)&Ws[(1 * 16 + fi) * SX + ks * 32 + quad * 8];
        short8 b2 = *(const short8*)&Ws[(2 * 16 + fi) * SX + ks * 32 + quad * 8];
        short8 b3 = *(const short8*)&Ws[(3 * 16 + fi) * SX + ks * 32 + quad * 8];
        acc0 = __builtin_amdgcn_mfma_f32_16x16x32_bf16(af, b0, acc0, 0, 0, 0);
        acc1 = __builtin_amdgcn_mfma_f32_16x16x32_bf16(af, b1, acc1, 0, 0, 0);
        acc2 = __builtin_amdgcn_mfma_f32_16x16x32_bf16(af, b2, acc2, 0, 0, 0);
        acc3 = __builtin_amdgcn_mfma_f32_16x16x32_bf16(af, b3, acc3, 0, 0, 0);
    }

    int nbase = blockIdx.x * 64 + wave * 16 + quad * 4;
    floatx4 accs[4] = { acc0, acc1, acc2, acc3 };
#pragma unroll
    for (int nt = 0; nt < 4; ++nt) {
        int col = nt * 16 + fi;
        float bias = b[col];
#pragma unroll
        for (int reg = 0; reg < 4; ++reg) {
            int node = nbase + reg;
            if (node < N) out[(size_t)node * 64 + col] = fmaxf(accs[nt][reg] + bias, 0.f);
        }
    }
}

// ---------------- EdgeConv stage 1 via MFMA: [m|p] = X @ [Wt | Wt+Wp]; md slice-major ----------------

__global__ __launch_bounds__(256) void k_e1_m(const float* __restrict__ X, const float* __restrict__ Wt,
                                              const float* __restrict__ Wp, const float* __restrict__ bt,
                                              const float* __restrict__ bp,
                                              unsigned short* __restrict__ md, float* __restrict__ pbuf, int N) {
    constexpr int SX = 72;
    __shared__ unsigned short Xs[64 * SX];
    __shared__ unsigned short Ws[128 * SX];
    int t = threadIdx.x;

    {
        int sn = t & 63;
        int gn = blockIdx.x * 64 + sn; if (gn >= N) gn = N - 1;
        int k0 = (t >> 6) * 16;
#pragma unroll
        for (int i = 0; i < 4; ++i) {
            float4 v = *(const float4*)&X[(size_t)gn * 64 + k0 + 4 * i];
            ushort4 u = { bfb(v.x), bfb(v.y), bfb(v.z), bfb(v.w) };
            *(ushort4*)&Xs[sn * SX + k0 + 4 * i] = u;
        }
    }
    for (int idx = t; idx < 4096; idx += 256) {
        int k = idx >> 6, n = idx & 63;
        float wt = Wt[idx];
        Ws[n * SX + k] = bfb(wt);
        Ws[(64 + n) * SX + k] = bfb(wt + Wp[idx]);
    }
    __syncthreads();

    int wave = t >> 6, lane = t & 63;
    int fi = lane & 15, quad = lane >> 4;
    int arow = wave * 16 + fi;

    floatx4 acc[8];
#pragma unroll
    for (int i = 0; i < 8; ++i) acc[i] = (floatx4){0.f,0.f,0.f,0.f};
#pragma unroll
    for (int ks = 0; ks < 2; ++ks) {
        short8 af = *(const short8*)&Xs[arow * SX + ks * 32 + quad * 8];
#pragma unroll
        for (int nt = 0; nt < 8; ++nt) {
            short8 bf = *(const short8*)&Ws[(nt * 16 + fi) * SX + ks * 32 + quad * 8];
            acc[nt] = __builtin_amdgcn_mfma_f32_16x16x32_bf16(af, bf, acc[nt], 0, 0, 0);
        }
    }

    int nbase = blockIdx.x * 64 + wave * 16 + quad * 4;
#pragma unroll
    for (int nt = 0; nt < 8; ++nt) {
        int col = nt * 16 + fi;
        if (col < 64) {
            int sl = col >> 3, off = col & 7;
#pragma unroll
            for (int reg = 0; reg < 4; ++reg) {
                int node = nbase + reg;
                if (node < N) md[((size_t)sl * N + node) * 8 + off] = bfb(acc[nt][reg]);
            }
        } else {
            int cc = col - 64;
            float bias = bt[cc] + bp[cc];
#pragma unroll
            for (int reg = 0; reg < 4; ++reg) {
                int node = nbase + reg;
                if (node < N) pbuf[(size_t)node * 64 + cc] = acc[nt][reg] + bias;
            }
        }
    }
}

// ---------------- graph mean pooling (segmented: gid is sorted) ----------------

__global__ __launch_bounds__(256) void k_pool(const float* __restrict__ h, const int* __restrict__ gid,
                                              float* __restrict__ out, float* __restrict__ gcnt, int N) {
    const int CHUNK = 128;
    int wave = blockIdx.x * 4 + (threadIdx.x >> 6);
    int lane = threadIdx.x & 63;
    int beg = wave * CHUNK;
    if (beg >= N) return;
    int end = beg + CHUNK < N ? beg + CHUNK : N;
    int gcur = gid[beg];
    float acc = 0.f;
    int cnt = 0;
    for (int n = beg; n < end; ++n) {
        int g = gid[n];
        float v = h[n * 64 + lane];
        if (g != gcur) {
            atomicAdd(&out[gcur * 64 + lane], acc);
            if (lane == 0) atomicAdd(&gcnt[gcur], (float)cnt);
            gcur = g; acc = 0.f; cnt = 0;
        }
        acc += v;
        ++cnt;
    }
    atomicAdd(&out[gcur * 64 + lane], acc);
    if (lane == 0) atomicAdd(&gcnt[gcur], (float)cnt);
}

__global__ __launch_bounds__(256) void k_div(float* __restrict__ out, const float* __restrict__ gcnt, int total) {
    int i = blockIdx.x * blockDim.x + threadIdx.x;
    if (i < total) out[i] /= fmaxf(gcnt[i >> 6], 1.f);
}

// ---------------- launcher ----------------

extern "C" void kernel_launch(void* const* d_in, const int* in_sizes, int n_in,
                              void* d_out, int out_size, void* d_ws, size_t ws_size,
                              hipStream_t stream) {
    const float* feat = (const float*)d_in[0];
    const int* src = (const int*)d_in[1];
    const int* dst = (const int*)d_in[2];
    const int* gid = (const int*)d_in[3];
    const float* W1 = (const float*)d_in[4];  const float* b1 = (const float*)d_in[5];
    const float* W2 = (const float*)d_in[6];  const float* b2 = (const float*)d_in[7];
    const float* W3 = (const float*)d_in[8];  const float* b3 = (const float*)d_in[9];
    const float* Wt1 = (const float*)d_in[10]; const float* bt1 = (const float*)d_in[11];
    const float* Wp1 = (const float*)d_in[12]; const float* bp1 = (const float*)d_in[13];
    const float* Wt2 = (const float*)d_in[14]; const float* bt2 = (const float*)d_in[15];
    const float* Wp2 = (const float*)d_in[16]; const float* bp2 = (const float*)d_in[17];
    float* out = (float*)d_out;

    const int N = in_sizes[0] / 16;
    const int E = in_sizes[1];
    const int G = out_size / 64;
    const int nb = (N + 255) >> 8;

    char* p = (char*)d_ws;
    auto alloc = [&](size_t nbytes) {
        void* r = (void*)p;
        p += (nbytes + 255) & ~(size_t)255;
        return r;
    };
    int* row_off  = (int*)alloc((size_t)(N + 1) * 4);
    int* csr      = (int*)alloc((size_t)E * 4);
    int* bcnt     = (int*)alloc(512 * 4);
    int* boff     = (int*)alloc(513 * 4);
    int* bcur     = (int*)alloc(512 * 4);
    float* dinv   = (float*)alloc((size_t)N * 4);
    float* bufA   = (float*)alloc((size_t)N * 64 * 4);
    float* bufB   = (float*)alloc((size_t)N * 64 * 4);
    float* bufC   = (float*)alloc((size_t)N * 64 * 4);
    float* bufD   = (float*)alloc((size_t)N * 64 * 4);
    unsigned short* md = (unsigned short*)alloc((size_t)N * 64 * 2);
    float* gcnt   = (float*)alloc((size_t)G * 4);

    unsigned* ebuf = (unsigned*)bufA;                              // dead until after CSR build
    unsigned short* hd = (unsigned short*)bufC;                    // slice-major 64-dim (or node-major 16-dim layer 1)
    unsigned short* xd = (unsigned short*)bufC + (size_t)N * 64;

    hipMemsetAsync(bcnt, 0, 512 * 4, stream);
    hipMemsetAsync(gcnt, 0, (size_t)G * 4, stream);
    hipMemsetAsync(d_out, 0, (size_t)out_size * 4, stream);

    const int nb16 = (N * 16 + 255) / 256;
    const int npool = ((N + 127) / 128 + 3) / 4;
    const int nbt = (N + 63) / 64;
    const int npart = (E + PCHUNK - 1) / PCHUNK;
    const int nbs = 8 * ((N + SLICE_NPB - 1) / SLICE_NPB);   // sliced gather grid

    // ---- bucketed CSR build v3
    k_bhist<<<256, 256, 0, stream>>>(dst, bcnt, E);
    k_scanBkt<<<1, 512, 0, stream>>>(bcnt, boff, bcur, nb, E);
    k_partA<<<npart, 256, 0, stream>>>(src, dst, bcur, ebuf, E);
    k_finish<<<nb, 256, 0, stream>>>(ebuf, boff, row_off, dinv, csr, N, E);

    // ---- Cheb layer 1 (IN=16, node-major tables)
    k_feat16<<<nb16, 256, 0, stream>>>(feat, dinv, hd, N * 16);
    k_aggr16<<<nb16, 256, 0, stream>>>(hd, nullptr, dinv, row_off, csr, bufA, xd, -1.f, 0.f, N);
    k_aggr16<<<nb16, 256, 0, stream>>>(xd, feat, dinv, row_off, csr, bufB, nullptr, -2.f, -1.f, N);
    k_cheb_m<16><<<nbt, 256, 0, stream>>>(feat, bufA, bufB, W1, b1, bufC, N);

    // ---- EdgeConv 1
    k_e1_m<<<nbt, 256, 0, stream>>>(bufC, Wt1, Wp1, bt1, bp1, md, bufB, N);
    k_e2s<<<nbs, 256, 0, stream>>>(md, bufB, row_off, csr, dinv, bufD, hd, N);

    // ---- Cheb layer 2
    k_aggr64s<<<nbs, 256, 0, stream>>>(hd, nullptr, dinv, row_off, csr, bufA, xd, -1.f, 0.f, N);
    k_aggr64s<<<nbs, 256, 0, stream>>>(xd, bufD, dinv, row_off, csr, bufB, nullptr, -2.f, -1.f, N);
    k_cheb_m<64><<<nbt, 256, 0, stream>>>(bufD, bufA, bufB, W2, b2, bufC, N);

    // ---- EdgeConv 2
    k_e1_m<<<nbt, 256, 0, stream>>>(bufC, Wt2, Wp2, bt2, bp2, md, bufB, N);
    k_e2s<<<nbs, 256, 0, stream>>>(md, bufB, row_off, csr, dinv, bufD, hd, N);

    // ---- Cheb layer 3
    k_aggr64s<<<nbs, 256, 0, stream>>>(hd, nullptr, dinv, row_off, csr, bufA, xd, -1.f, 0.f, N);
    k_aggr64s<<<nbs, 256, 0, stream>>>(xd, bufD, dinv, row_off, csr, bufB, nullptr, -2.f, -1.f, N);
    k_cheb_m<64><<<nbt, 256, 0, stream>>>(bufD, bufA, bufB, W3, b3, bufC, N);

    // ---- per-graph mean pooling
    k_pool<<<npool, 256, 0, stream>>>(bufC, gid, out, gcnt, N);
    k_div<<<(out_size + 255) / 256, 256, 0, stream>>>(out, gcnt, out_size);
}

// Round 15
// 664.004 us; speedup vs baseline: 1.2477x; 1.2477x over previous
//
#include <hip/hip_runtime.h>
#include <hip/hip_bf16.h>
#include <math.h>

typedef __attribute__((ext_vector_type(8))) short short8;
typedef __attribute__((ext_vector_type(4))) float floatx4;

__device__ __forceinline__ unsigned short bfb(float x) {
    union { __hip_bfloat16 h; unsigned short u; } c;
    c.h = __float2bfloat16(x);
    return c.u;
}
__device__ __forceinline__ float bf2f(unsigned short u) {
    union { unsigned int i; float f; } c;
    c.i = ((unsigned int)u) << 16;
    return c.f;
}

// ---------------- bucketed CSR build v3 (R13-verified) ----------------
// bucket = dst>>8 (256 nodes). ebuf entry = (src<<8)|(dst&255). Fused tail: row_off
// inside bucket b = boff[b] + local LDS scan; scatter with LDS cursors (bucket-owned
// contiguous csr span -> full-line evictions, no cross-XCD line sharing).

__global__ __launch_bounds__(256) void k_bhist(const int* __restrict__ dst, int* __restrict__ bcnt, int E) {
    __shared__ int h[512];
    int t = threadIdx.x;
    for (int i = t; i < 512; i += 256) h[i] = 0;
    __syncthreads();
    int step = gridDim.x * 256;
    for (int i = blockIdx.x * 256 + t; i < E; i += step) atomicAdd(&h[dst[i] >> 8], 1);
    __syncthreads();
    for (int i = t; i < 512; i += 256) if (h[i]) atomicAdd(&bcnt[i], h[i]);
}

__global__ __launch_bounds__(512) void k_scanBkt(const int* __restrict__ bcnt, int* __restrict__ boff,
                                                 int* __restrict__ bcur, int nb, int E) {
    __shared__ int s[512];
    int t = threadIdx.x;
    int v = (t < nb) ? bcnt[t] : 0;
    s[t] = v;
    __syncthreads();
    for (int off = 1; off < 512; off <<= 1) {
        int x = (t >= off) ? s[t - off] : 0;
        __syncthreads();
        s[t] += x;
        __syncthreads();
    }
    if (t < nb) { boff[t] = s[t] - v; bcur[t] = s[t] - v; }
    if (t == 0) boff[nb] = E;
}

#define PCHUNK 8192

__global__ __launch_bounds__(256) void k_partA(const int* __restrict__ src, const int* __restrict__ dst,
                                               int* __restrict__ bcur, unsigned* __restrict__ ebuf, int E) {
    __shared__ int h[512];
    __shared__ int base[512];
    int t = threadIdx.x;
    for (int i = t; i < 512; i += 256) h[i] = 0;
    __syncthreads();
    int start = blockIdx.x * PCHUNK;
    int end = start + PCHUNK < E ? start + PCHUNK : E;
    for (int i = start + t; i < end; i += 256) atomicAdd(&h[dst[i] >> 8], 1);
    __syncthreads();
    for (int i = t; i < 512; i += 256) {
        int c = h[i];
        base[i] = c ? atomicAdd(&bcur[i], c) : 0;
        h[i] = 0;
    }
    __syncthreads();
    for (int i = start + t; i < end; i += 256) {
        int d = dst[i];
        int b = d >> 8;
        int r = atomicAdd(&h[b], 1);
        ebuf[base[b] + r] = ((unsigned)src[i] << 8) | (unsigned)(d & 255);
    }
}

__global__ __launch_bounds__(256) void k_finish(const unsigned* __restrict__ ebuf, const int* __restrict__ boff,
                                                int* __restrict__ row_off, float* __restrict__ dinv,
                                                int* __restrict__ csr, int N, int E) {
    __shared__ int h[256];
    __shared__ int sc[256];
    __shared__ int cur[256];
    int b = blockIdx.x, t = threadIdx.x;
    h[t] = 0;
    __syncthreads();
    int beg = boff[b], end = boff[b + 1];
    for (int e = beg + t; e < end; e += 256) atomicAdd(&h[ebuf[e] & 255], 1);
    __syncthreads();
    int v = h[t];
    sc[t] = v;
    __syncthreads();
    for (int off = 1; off < 256; off <<= 1) {
        int x = (t >= off) ? sc[t - off] : 0;
        __syncthreads();
        sc[t] += x;
        __syncthreads();
    }
    int node = (b << 8) + t;
    int excl = beg + sc[t] - v;
    if (node < N) {
        row_off[node] = excl;
        dinv[node] = rsqrtf((float)(v > 1 ? v : 1));
    }
    cur[t] = excl;
    if (b == 0 && t == 0) row_off[N] = E;
    __syncthreads();
    for (int e = beg + t; e < end; e += 256) {
        unsigned ed = ebuf[e];
        int pos = atomicAdd(&cur[ed & 255], 1);
        csr[pos] = (int)(ed >> 8);
    }
}

// ---------------- feat -> bf16 pre-scaled ----------------

__global__ __launch_bounds__(256) void k_feat16(const float* __restrict__ feat, const float* __restrict__ dinv,
                                                unsigned short* __restrict__ featd, int total) {
    int i = blockIdx.x * 256 + threadIdx.x;
    if (i < total) featd[i] = bfb(feat[i] * dinv[i >> 4]);
}

// ---------------- 16-dim Chebyshev aggregation (bf16 gather) ----------------

__global__ __launch_bounds__(256) void k_aggr16(const unsigned short* __restrict__ Xd, const float* __restrict__ Z,
                                                const float* __restrict__ dinv,
                                                const int* __restrict__ row_off, const int* __restrict__ csr,
                                                float* __restrict__ out, unsigned short* __restrict__ outd,
                                                float alpha, float beta, int N) {
    const int D = 16;
    int t = blockIdx.x * blockDim.x + threadIdx.x;
    int node = t / D;
    int d = t % D;
    if (node >= N) return;
    int beg = row_off[node], end = row_off[node + 1];
    float a0 = 0.f, a1 = 0.f, a2 = 0.f, a3 = 0.f;
    int j = beg;
    for (; j + 3 < end; j += 4) {
        int s0 = csr[j], s1 = csr[j + 1], s2 = csr[j + 2], s3 = csr[j + 3];
        a0 += bf2f(Xd[s0 * D + d]);
        a1 += bf2f(Xd[s1 * D + d]);
        a2 += bf2f(Xd[s2 * D + d]);
        a3 += bf2f(Xd[s3 * D + d]);
    }
    for (; j < end; ++j) a0 += bf2f(Xd[csr[j] * D + d]);
    float acc = (a0 + a1) + (a2 + a3);
    float dn = dinv[node];
    float v = alpha * dn * acc;
    if (Z) v += beta * Z[node * D + d];
    out[node * D + d] = v;
    if (outd) outd[node * D + d] = bfb(v * dn);
}

// ---------------- 64-dim Chebyshev aggregation, QUAD-EDGE gather (R12/R13-verified) ----------------
// At the L3 random-line service floor: R10/R12/R14 access variants all pin at
// ~99MB FETCH / ~2.4 TB/s (each of 8 non-coherent XCD L2s streams the 12.8MB table).

__global__ __launch_bounds__(256) void k_aggr64(const unsigned short* __restrict__ Xd, const float* __restrict__ Z,
                                                const float* __restrict__ dinv,
                                                const int* __restrict__ row_off, const int* __restrict__ csr,
                                                float* __restrict__ out, unsigned short* __restrict__ outd,
                                                float alpha, float beta, int N) {
    int node = blockIdx.x * 4 + (threadIdx.x >> 6);
    if (node >= N) return;
    int lane = threadIdx.x & 63;
    int g = lane >> 4;
    int c4 = (lane & 15) * 4;
    int beg = row_off[node], end = row_off[node + 1];
    float a0 = 0.f, a1 = 0.f, a2 = 0.f, a3 = 0.f;
    float b0 = 0.f, b1 = 0.f, b2 = 0.f, b3 = 0.f;
    int j = beg;
    for (; j + 7 < end; j += 8) {
        int sA = csr[j + g];
        int sB = csr[j + 4 + g];
        ushort4 xA = *(const ushort4*)&Xd[sA * 64 + c4];
        ushort4 xB = *(const ushort4*)&Xd[sB * 64 + c4];
        a0 += bf2f(xA.x); a1 += bf2f(xA.y); a2 += bf2f(xA.z); a3 += bf2f(xA.w);
        b0 += bf2f(xB.x); b1 += bf2f(xB.y); b2 += bf2f(xB.z); b3 += bf2f(xB.w);
    }
    for (; j < end; j += 4) {
        int idx = j + g;
        int s = csr[idx < end ? idx : end - 1];
        ushort4 x = *(const ushort4*)&Xd[s * 64 + c4];
        if (idx < end) {
            a0 += bf2f(x.x); a1 += bf2f(x.y); a2 += bf2f(x.z); a3 += bf2f(x.w);
        }
    }
    a0 += b0; a1 += b1; a2 += b2; a3 += b3;
    a0 += __shfl_xor(a0, 16); a0 += __shfl_xor(a0, 32);
    a1 += __shfl_xor(a1, 16); a1 += __shfl_xor(a1, 32);
    a2 += __shfl_xor(a2, 16); a2 += __shfl_xor(a2, 32);
    a3 += __shfl_xor(a3, 16); a3 += __shfl_xor(a3, 32);
    if (g == 0) {
        float dn = dinv[node];
        float v0 = alpha * dn * a0;
        float v1 = alpha * dn * a1;
        float v2 = alpha * dn * a2;
        float v3 = alpha * dn * a3;
        if (Z) {
            float4 zv = *(const float4*)&Z[(size_t)node * 64 + c4];
            v0 += beta * zv.x; v1 += beta * zv.y; v2 += beta * zv.z; v3 += beta * zv.w;
        }
        float4 r = { v0, v1, v2, v3 };
        *(float4*)&out[(size_t)node * 64 + c4] = r;
        if (outd) {
            ushort4 u = { bfb(v0 * dn), bfb(v1 * dn), bfb(v2 * dn), bfb(v3 * dn) };
            *(ushort4*)&outd[(size_t)node * 64 + c4] = u;
        }
    }
}

// ---------------- Cheb matmul via MFMA 16x16x32 bf16 (R11-verified) ----------------

template <int KDIM>
__global__ __launch_bounds__(256) void k_cheb_m(const float* __restrict__ X0, const float* __restrict__ X1,
                                                const float* __restrict__ X2, const float* __restrict__ W,
                                                const float* __restrict__ b, float* __restrict__ out, int N) {
    constexpr int KT = (KDIM == 16) ? 64 : 3 * KDIM;
    constexpr int SX = KT + 8;
    __shared__ unsigned short Xs[64 * SX];
    __shared__ unsigned short Ws[64 * SX];
    int t = threadIdx.x;

    {
        int sn = t & 63;
        int gn = blockIdx.x * 64 + sn; if (gn >= N) gn = N - 1;
        int k0 = (t >> 6) * (KDIM / 4);
        const float* Xp[3] = { X0, X1, X2 };
#pragma unroll
        for (int a = 0; a < 3; ++a) {
            const float* X = Xp[a];
#pragma unroll
            for (int i = 0; i < KDIM / 16; ++i) {
                float4 v = *(const float4*)&X[(size_t)gn * KDIM + k0 + 4 * i];
                ushort4 u = { bfb(v.x), bfb(v.y), bfb(v.z), bfb(v.w) };
                *(ushort4*)&Xs[sn * SX + a * KDIM + k0 + 4 * i] = u;
            }
        }
        if (KDIM == 16) {
            int kp = 48 + (t >> 6) * 4;
            ushort4 z = { 0, 0, 0, 0 };
            *(ushort4*)&Xs[sn * SX + kp] = z;
        }
    }
    for (int idx = t; idx < 3 * KDIM * 64; idx += 256) {
        int a = idx / (KDIM * 64);
        int r = idx % (KDIM * 64);
        int k = r >> 6, n = r & 63;
        Ws[n * SX + a * KDIM + k] = bfb(W[idx]);
    }
    if (KDIM == 16) {
        for (int idx = t; idx < 1024; idx += 256) {
            int n = idx & 63, k = 48 + (idx >> 6);
            Ws[n * SX + k] = 0;
        }
    }
    __syncthreads();

    int wave = t >> 6, lane = t & 63;
    int fi = lane & 15, quad = lane >> 4;
    int arow = wave * 16 + fi;

    floatx4 acc0 = {0.f,0.f,0.f,0.f}, acc1 = {0.f,0.f,0.f,0.f}, acc2 = {0.f,0.f,0.f,0.f}, acc3 = {0.f,0.f,0.f,0.f};
#pragma unroll
    for (int ks = 0; ks < KT / 32; ++ks) {
        short8 af = *(const short8*)&Xs[arow * SX + ks * 32 + quad * 8];
        short8 b0 = *(const short8*)&Ws[(0 * 16 + fi) * SX + ks * 32 + quad * 8];
        short8 b1 = *(const short8*)&Ws[(1 * 16 + fi) * SX + ks * 32 + quad * 8];
        short8 b2 = *(const short8*)&Ws[(2 * 16 + fi) * SX + ks * 32 + quad * 8];
        short8 b3 = *(const short8*)&Ws[(3 * 16 + fi) * SX + ks * 32 + quad * 8];
        acc0 = __builtin_amdgcn_mfma_f32_16x16x32_bf16(af, b0, acc0, 0, 0, 0);
        acc1 = __builtin_amdgcn_mfma_f32_16x16x32_bf16(af, b1, acc1, 0, 0, 0);
        acc2 = __builtin_amdgcn_mfma_f32_16x16x32_bf16(af, b2, acc2, 0, 0, 0);
        acc3 = __builtin_amdgcn_mfma_f32_16x16x32_bf16(af, b3, acc3, 0, 0, 0);
    }

    int nbase = blockIdx.x * 64 + wave * 16 + quad * 4;
    floatx4 accs[4] = { acc0, acc1, acc2, acc3 };
#pragma unroll
    for (int nt = 0; nt < 4; ++nt) {
        int col = nt * 16 + fi;
        float bias = b[col];
#pragma unroll
        for (int reg = 0; reg < 4; ++reg) {
            int node = nbase + reg;
            if (node < N) out[(size_t)node * 64 + col] = fmaxf(accs[nt][reg] + bias, 0.f);
        }
    }
}

// ---------------- EdgeConv stage 1 via MFMA: [m|p] = X @ [Wt | Wt+Wp] (R11) ----------------

__global__ __launch_bounds__(256) void k_e1_m(const float* __restrict__ X, const float* __restrict__ Wt,
                                              const float* __restrict__ Wp, const float* __restrict__ bt,
                                              const float* __restrict__ bp,
                                              unsigned short* __restrict__ md, float* __restrict__ pbuf, int N) {
    constexpr int SX = 72;
    __shared__ unsigned short Xs[64 * SX];
    __shared__ unsigned short Ws[128 * SX];
    int t = threadIdx.x;

    {
        int sn = t & 63;
        int gn = blockIdx.x * 64 + sn; if (gn >= N) gn = N - 1;
        int k0 = (t >> 6) * 16;
#pragma unroll
        for (int i = 0; i < 4; ++i) {
            float4 v = *(const float4*)&X[(size_t)gn * 64 + k0 + 4 * i];
            ushort4 u = { bfb(v.x), bfb(v.y), bfb(v.z), bfb(v.w) };
            *(ushort4*)&Xs[sn * SX + k0 + 4 * i] = u;
        }
    }
    for (int idx = t; idx < 4096; idx += 256) {
        int k = idx >> 6, n = idx & 63;
        float wt = Wt[idx];
        Ws[n * SX + k] = bfb(wt);
        Ws[(64 + n) * SX + k] = bfb(wt + Wp[idx]);
    }
    __syncthreads();

    int wave = t >> 6, lane = t & 63;
    int fi = lane & 15, quad = lane >> 4;
    int arow = wave * 16 + fi;

    floatx4 acc[8];
#pragma unroll
    for (int i = 0; i < 8; ++i) acc[i] = (floatx4){0.f,0.f,0.f,0.f};
#pragma unroll
    for (int ks = 0; ks < 2; ++ks) {
        short8 af = *(const short8*)&Xs[arow * SX + ks * 32 + quad * 8];
#pragma unroll
        for (int nt = 0; nt < 8; ++nt) {
            short8 bf = *(const short8*)&Ws[(nt * 16 + fi) * SX + ks * 32 + quad * 8];
            acc[nt] = __builtin_amdgcn_mfma_f32_16x16x32_bf16(af, bf, acc[nt], 0, 0, 0);
        }
    }

    int nbase = blockIdx.x * 64 + wave * 16 + quad * 4;
#pragma unroll
    for (int nt = 0; nt < 8; ++nt) {
        int col = nt * 16 + fi;
        if (col < 64) {
#pragma unroll
            for (int reg = 0; reg < 4; ++reg) {
                int node = nbase + reg;
                if (node < N) md[(size_t)node * 64 + col] = bfb(acc[nt][reg]);
            }
        } else {
            int cc = col - 64;
            float bias = bt[cc] + bp[cc];
#pragma unroll
            for (int reg = 0; reg < 4; ++reg) {
                int node = nbase + reg;
                if (node < N) pbuf[(size_t)node * 64 + cc] = acc[nt][reg] + bias;
            }
        }
    }
}

// ---------------- EdgeConv stage 2, QUAD-EDGE bf16 gather (R12/R13-verified) ----------------

__global__ __launch_bounds__(256) void k_e2_b(const unsigned short* __restrict__ md, const float* __restrict__ pbuf,
                                              const int* __restrict__ row_off, const int* __restrict__ csr,
                                              const float* __restrict__ dinv, float* __restrict__ out,
                                              unsigned short* __restrict__ outd, int N) {
    int node = blockIdx.x * 4 + (threadIdx.x >> 6);
    if (node >= N) return;
    int lane = threadIdx.x & 63;
    int g = lane >> 4;
    int c4 = (lane & 15) * 4;
    int beg = row_off[node], end = row_off[node + 1];
    float a0 = -INFINITY, a1 = -INFINITY, a2 = -INFINITY, a3 = -INFINITY;
    float b0 = -INFINITY, b1 = -INFINITY, b2 = -INFINITY, b3 = -INFINITY;
    int j = beg;
    for (; j + 7 < end; j += 8) {
        int sA = csr[j + g];
        int sB = csr[j + 4 + g];
        ushort4 xA = *(const ushort4*)&md[sA * 64 + c4];
        ushort4 xB = *(const ushort4*)&md[sB * 64 + c4];
        a0 = fmaxf(a0, -bf2f(xA.x)); a1 = fmaxf(a1, -bf2f(xA.y));
        a2 = fmaxf(a2, -bf2f(xA.z)); a3 = fmaxf(a3, -bf2f(xA.w));
        b0 = fmaxf(b0, -bf2f(xB.x)); b1 = fmaxf(b1, -bf2f(xB.y));
        b2 = fmaxf(b2, -bf2f(xB.z)); b3 = fmaxf(b3, -bf2f(xB.w));
    }
    for (; j < end; j += 4) {
        int idx = j + g;
        int s = csr[idx < end ? idx : end - 1];
        ushort4 x = *(const ushort4*)&md[s * 64 + c4];
        if (idx < end) {
            a0 = fmaxf(a0, -bf2f(x.x)); a1 = fmaxf(a1, -bf2f(x.y));
            a2 = fmaxf(a2, -bf2f(x.z)); a3 = fmaxf(a3, -bf2f(x.w));
        }
    }
    a0 = fmaxf(a0, b0); a1 = fmaxf(a1, b1); a2 = fmaxf(a2, b2); a3 = fmaxf(a3, b3);
    a0 = fmaxf(a0, __shfl_xor(a0, 16)); a0 = fmaxf(a0, __shfl_xor(a0, 32));
    a1 = fmaxf(a1, __shfl_xor(a1, 16)); a1 = fmaxf(a1, __shfl_xor(a1, 32));
    a2 = fmaxf(a2, __shfl_xor(a2, 16)); a2 = fmaxf(a2, __shfl_xor(a2, 32));
    a3 = fmaxf(a3, __shfl_xor(a3, 16)); a3 = fmaxf(a3, __shfl_xor(a3, 32));
    if (g == 0) {
        float r0 = 0.f, r1 = 0.f, r2 = 0.f, r3 = 0.f;
        if (end > beg) {
            float4 pv = *(const float4*)&pbuf[(size_t)node * 64 + c4];
            r0 = fmaxf(pv.x + a0, 0.f);
            r1 = fmaxf(pv.y + a1, 0.f);
            r2 = fmaxf(pv.z + a2, 0.f);
            r3 = fmaxf(pv.w + a3, 0.f);
        }
        float4 r = { r0, r1, r2, r3 };
        *(float4*)&out[(size_t)node * 64 + c4] = r;
        float dn = dinv[node];
        ushort4 u = { bfb(r0 * dn), bfb(r1 * dn), bfb(r2 * dn), bfb(r3 * dn) };
        *(ushort4*)&outd[(size_t)node * 64 + c4] = u;
    }
}

// ---------------- graph mean pooling (segmented: gid is sorted) ----------------

__global__ __launch_bounds__(256) void k_pool(const float* __restrict__ h, const int* __restrict__ gid,
                                              float* __restrict__ out, float* __restrict__ gcnt, int N) {
    const int CHUNK = 128;
    int wave = blockIdx.x * 4 + (threadIdx.x >> 6);
    int lane = threadIdx.x & 63;
    int beg = wave * CHUNK;
    if (beg >= N) return;
    int end = beg + CHUNK < N ? beg + CHUNK : N;
    int gcur = gid[beg];
    float acc = 0.f;
    int cnt = 0;
    for (int n = beg; n < end; ++n) {
        int g = gid[n];
        float v = h[n * 64 + lane];
        if (g != gcur) {
            atomicAdd(&out[gcur * 64 + lane], acc);
            if (lane == 0) atomicAdd(&gcnt[gcur], (float)cnt);
            gcur = g; acc = 0.f; cnt = 0;
        }
        acc += v;
        ++cnt;
    }
    atomicAdd(&out[gcur * 64 + lane], acc);
    if (lane == 0) atomicAdd(&gcnt[gcur], (float)cnt);
}

__global__ __launch_bounds__(256) void k_div(float* __restrict__ out, const float* __restrict__ gcnt, int total) {
    int i = blockIdx.x * blockDim.x + threadIdx.x;
    if (i < total) out[i] /= fmaxf(gcnt[i >> 6], 1.f);
}

// ---------------- launcher ----------------

extern "C" void kernel_launch(void* const* d_in, const int* in_sizes, int n_in,
                              void* d_out, int out_size, void* d_ws, size_t ws_size,
                              hipStream_t stream) {
    const float* feat = (const float*)d_in[0];
    const int* src = (const int*)d_in[1];
    const int* dst = (const int*)d_in[2];
    const int* gid = (const int*)d_in[3];
    const float* W1 = (const float*)d_in[4];  const float* b1 = (const float*)d_in[5];
    const float* W2 = (const float*)d_in[6];  const float* b2 = (const float*)d_in[7];
    const float* W3 = (const float*)d_in[8];  const float* b3 = (const float*)d_in[9];
    const float* Wt1 = (const float*)d_in[10]; const float* bt1 = (const float*)d_in[11];
    const float* Wp1 = (const float*)d_in[12]; const float* bp1 = (const float*)d_in[13];
    const float* Wt2 = (const float*)d_in[14]; const float* bt2 = (const float*)d_in[15];
    const float* Wp2 = (const float*)d_in[16]; const float* bp2 = (const float*)d_in[17];
    float* out = (float*)d_out;

    const int N = in_sizes[0] / 16;
    const int E = in_sizes[1];
    const int G = out_size / 64;
    const int nb = (N + 255) >> 8;

    char* p = (char*)d_ws;
    auto alloc = [&](size_t nbytes) {
        void* r = (void*)p;
        p += (nbytes + 255) & ~(size_t)255;
        return r;
    };
    int* row_off  = (int*)alloc((size_t)(N + 1) * 4);
    int* csr      = (int*)alloc((size_t)E * 4);
    int* bcnt     = (int*)alloc(512 * 4);
    int* boff     = (int*)alloc(513 * 4);
    int* bcur     = (int*)alloc(512 * 4);
    float* dinv   = (float*)alloc((size_t)N * 4);
    float* bufA   = (float*)alloc((size_t)N * 64 * 4);
    float* bufB   = (float*)alloc((size_t)N * 64 * 4);
    float* bufC   = (float*)alloc((size_t)N * 64 * 4);
    float* bufD   = (float*)alloc((size_t)N * 64 * 4);
    unsigned short* md = (unsigned short*)alloc((size_t)N * 64 * 2);
    float* gcnt   = (float*)alloc((size_t)G * 4);

    unsigned* ebuf = (unsigned*)bufA;   // alias: bufA dead until after CSR build
    unsigned short* hd = (unsigned short*)bufC;
    unsigned short* xd = (unsigned short*)bufC + (size_t)N * 64;

    hipMemsetAsync(bcnt, 0, 512 * 4, stream);
    hipMemsetAsync(gcnt, 0, (size_t)G * 4, stream);
    hipMemsetAsync(d_out, 0, (size_t)out_size * 4, stream);

    const int nb16 = (N * 16 + 255) / 256;
    const int nbw = (N + 3) / 4;
    const int npool = ((N + 127) / 128 + 3) / 4;
    const int nbt = (N + 63) / 64;
    const int npart = (E + PCHUNK - 1) / PCHUNK;

    // ---- bucketed CSR build v3 (4 launches)
    k_bhist<<<256, 256, 0, stream>>>(dst, bcnt, E);
    k_scanBkt<<<1, 512, 0, stream>>>(bcnt, boff, bcur, nb, E);
    k_partA<<<npart, 256, 0, stream>>>(src, dst, bcur, ebuf, E);
    k_finish<<<nb, 256, 0, stream>>>(ebuf, boff, row_off, dinv, csr, N, E);

    // ---- Cheb layer 1 (IN=16)
    k_feat16<<<nb16, 256, 0, stream>>>(feat, dinv, hd, N * 16);
    k_aggr16<<<nb16, 256, 0, stream>>>(hd, nullptr, dinv, row_off, csr, bufA, xd, -1.f, 0.f, N);
    k_aggr16<<<nb16, 256, 0, stream>>>(xd, feat, dinv, row_off, csr, bufB, nullptr, -2.f, -1.f, N);
    k_cheb_m<16><<<nbt, 256, 0, stream>>>(feat, bufA, bufB, W1, b1, bufC, N);

    // ---- EdgeConv 1
    k_e1_m<<<nbt, 256, 0, stream>>>(bufC, Wt1, Wp1, bt1, bp1, md, bufB, N);
    k_e2_b<<<nbw, 256, 0, stream>>>(md, bufB, row_off, csr, dinv, bufD, hd, N);

    // ---- Cheb layer 2
    k_aggr64<<<nbw, 256, 0, stream>>>(hd, nullptr, dinv, row_off, csr, bufA, xd, -1.f, 0.f, N);
    k_aggr64<<<nbw, 256, 0, stream>>>(xd, bufD, dinv, row_off, csr, bufB, nullptr, -2.f, -1.f, N);
    k_cheb_m<64><<<nbt, 256, 0, stream>>>(bufD, bufA, bufB, W2, b2, bufC, N);

    // ---- EdgeConv 2
    k_e1_m<<<nbt, 256, 0, stream>>>(bufC, Wt2, Wp2, bt2, bp2, md, bufB, N);
    k_e2_b<<<nbw, 256, 0, stream>>>(md, bufB, row_off, csr, dinv, bufD, hd, N);

    // ---- Cheb layer 3
    k_aggr64<<<nbw, 256, 0, stream>>>(hd, nullptr, dinv, row_off, csr, bufA, xd, -1.f, 0.f, N);
    k_aggr64<<<nbw, 256, 0, stream>>>(xd, bufD, dinv, row_off, csr, bufB, nullptr, -2.f, -1.f, N);
    k_cheb_m<64><<<nbt, 256, 0, stream>>>(bufD, bufA, bufB, W3, b3, bufC, N);

    // ---- per-graph mean pooling
    k_pool<<<npool, 256, 0, stream>>>(bufC, gid, out, gcnt, N);
    k_div<<<(out_size + 255) / 256, 256, 0, stream>>>(out, gcnt, out_size);
}